// Round 5
// baseline (107.105 us; speedup 1.0000x reference)
//
#include <hip/hip_runtime.h>
#include <hip/hip_bf16.h>
#include <stdint.h>

#define NB    4096
#define NROWS 8192
#define DIM   512
#define BMM   256                 // tile M = N = 256
#define BKK   64                  // K-tile
#define NKT   (DIM / BKK)         // 8 K-tiles
#define TG    32                  // tile grid 32x32
#define NTRI  (TG * (TG + 1) / 2) // 528 = 8 * 66

typedef __attribute__((ext_vector_type(8))) short          bf16x8;
typedef __attribute__((ext_vector_type(4))) float          f32x4;
typedef __attribute__((ext_vector_type(8))) unsigned short u16x8;

__device__ __forceinline__ unsigned short f2bf(float f) {
  uint32_t u = __float_as_uint(f);
  u += 0x7fffu + ((u >> 16) & 1u);
  return (unsigned short)(u >> 16);
}
__device__ __forceinline__ float bf2f(unsigned short h) {
  return __uint_as_float(((uint32_t)h) << 16);
}
__device__ __forceinline__ void gload_lds16(const void* g, void* l) {
  __builtin_amdgcn_global_load_lds(
      (const __attribute__((address_space(1))) void*)g,
      (__attribute__((address_space(3))) void*)l, 16, 0, 0);
}

// ---- Kernel 1: normalize rows -> bf16 P, fused pos partials, zero rowsum --
__global__ __launch_bounds__(256) void normalize_pos_kernel(
    const float* __restrict__ zi, const float* __restrict__ zj,
    unsigned short* __restrict__ p, float* __restrict__ rowsum,
    float* __restrict__ posp) {
  __shared__ float ws4[4];
  const int wave = threadIdx.x >> 6;
  const int lane = threadIdx.x & 63;
  const int i    = blockIdx.x * 4 + wave;

  int gt = blockIdx.x * 256 + threadIdx.x;
  if (gt < NROWS) rowsum[gt] = 0.f;

  const float4* sa = (const float4*)(zi + (size_t)i * DIM);
  const float4* sb = (const float4*)(zj + (size_t)i * DIM);
  float4 a0 = sa[lane * 2], a1 = sa[lane * 2 + 1];
  float4 b0 = sb[lane * 2], b1 = sb[lane * 2 + 1];
  float va[8] = {a0.x, a0.y, a0.z, a0.w, a1.x, a1.y, a1.z, a1.w};
  float vb[8] = {b0.x, b0.y, b0.z, b0.w, b1.x, b1.y, b1.z, b1.w};
  float ssa = 0.f, ssb = 0.f;
#pragma unroll
  for (int j = 0; j < 8; ++j) { ssa += va[j] * va[j]; ssb += vb[j] * vb[j]; }
#pragma unroll
  for (int off = 32; off; off >>= 1) {
    ssa += __shfl_xor(ssa, off);
    ssb += __shfl_xor(ssb, off);
  }
  float inva = rsqrtf(ssa), invb = rsqrtf(ssb);
  u16x8 ha, hb;
#pragma unroll
  for (int j = 0; j < 8; ++j) { ha[j] = f2bf(va[j] * inva); hb[j] = f2bf(vb[j] * invb); }
  *(u16x8*)(p + (size_t)i * DIM + lane * 8)        = ha;
  *(u16x8*)(p + (size_t)(i + NB) * DIM + lane * 8) = hb;

  float d = 0.f;
#pragma unroll
  for (int j = 0; j < 8; ++j) d += bf2f(ha[j]) * bf2f(hb[j]);
#pragma unroll
  for (int off = 32; off; off >>= 1) d += __shfl_xor(d, off);
  if (lane == 0) ws4[wave] = d;
  __syncthreads();
  if (threadIdx.x == 0)
    posp[blockIdx.x] = 4.0f * (ws4[0] + ws4[1] + ws4[2] + ws4[3]);
}

// ---- Kernel 2: 256x256-tile symmetric S=2*P*P^T -> exp -> row+col sums ----
// 8 waves (2m x 4n), per-wave C = 128x64. 4 phases per K-tile, counted vmcnt,
// barriers only at ph0/ph2, setprio around MFMA clusters.
// LDS layout [256][64] bf16 per operand per buffer; 16B chunk swizzled by
// chunk ^= (row&7) via pre-swizzled global source (linear LDS dest).
__global__ __launch_bounds__(512, 2) void simexp_kernel(
    const unsigned short* __restrict__ p, float* __restrict__ rowsum) {
  __shared__ __align__(16) unsigned short As[2][BMM * BKK];  // 2 x 32 KB
  __shared__ __align__(16) unsigned short Bs[2][BMM * BKK];  // 2 x 32 KB

  // triangular tile id: XCD x gets tiles [x*66, x*66+66)
  const int bid = blockIdx.x;
  const int ti  = (bid & 7) * 66 + (bid >> 3);
  int bi = 0;
  while ((bi + 1) * (65 - (bi + 1)) / 2 <= ti) ++bi;
  const int bj   = bi + (ti - bi * (65 - bi) / 2);
  const bool diag = (bi == bj);

  const int tid  = threadIdx.x;
  const int wave = tid >> 6;
  const int lane = tid & 63;
  const int wm   = wave >> 2;      // 0..1
  const int wn   = wave & 3;       // 0..3
  const int frow = lane & 15;
  const int kc   = lane >> 4;      // 0..3

  const unsigned short* pa = p + (size_t)(bi * BMM) * DIM;
  const unsigned short* pb = p + (size_t)(bj * BMM) * DIM;

  // staging: quarter q covers 64 rows of one operand; wave handles 8 rows
  const int srow8 = lane >> 3;               // 0..7 row within wave's stripe
  const int gch   = (lane & 7) ^ srow8;      // pre-swizzled 16B chunk

#define STAGE_Q(src, dst, q, kt)                                              \
  gload_lds16((src) + (size_t)((q) * 64 + wave * 8 + srow8) * DIM + (kt) +    \
                  gch * 8,                                                    \
              (dst) + ((q) * 64 + wave * 8) * 128)

  // ds_read bases: byte = row*128 + ((kk*4+kc)^(frow&7))*16
  const int e7    = frow & 7;
  const int cb0   = ((0 + kc) ^ e7) * 16;
  const int cb1   = ((4 + kc) ^ e7) * 16;
  const int aoff0 = (wm * 128 + frow) * 128 + cb0;
  const int aoff1 = (wm * 128 + frow) * 128 + cb1;
  const int boff0 = (wn * 64 + frow) * 128 + cb0;
  const int boff1 = (wn * 64 + frow) * 128 + cb1;

  f32x4 acc[8][4] = {};

  // prologue: stage tile 0 in vmcnt order B0,B1,B2,B3,A0,A2,A1,A3
  STAGE_Q(pb, (char*)Bs[0], 0, 0); STAGE_Q(pb, (char*)Bs[0], 1, 0);
  STAGE_Q(pb, (char*)Bs[0], 2, 0); STAGE_Q(pb, (char*)Bs[0], 3, 0);
  STAGE_Q(pa, (char*)As[0], 0, 0); STAGE_Q(pa, (char*)As[0], 2, 0);
  STAGE_Q(pa, (char*)As[0], 1, 0); STAGE_Q(pa, (char*)As[0], 3, 0);

#define PHASE(ph, STAGES)                                                     \
  {                                                                           \
    bf16x8 a00 = *(const bf16x8*)(Ab + aoff0 + (2 * (ph)) * 2048);            \
    bf16x8 a01 = *(const bf16x8*)(Ab + aoff1 + (2 * (ph)) * 2048);            \
    bf16x8 a10 = *(const bf16x8*)(Ab + aoff0 + (2 * (ph) + 1) * 2048);        \
    bf16x8 a11 = *(const bf16x8*)(Ab + aoff1 + (2 * (ph) + 1) * 2048);        \
    STAGES;                                                                   \
    __builtin_amdgcn_s_setprio(1);                                            \
    _Pragma("unroll")                                                         \
    for (int nf = 0; nf < 4; ++nf) {                                          \
      acc[2 * (ph)][nf] = __builtin_amdgcn_mfma_f32_16x16x32_bf16(            \
          a00, bF[nf][0], acc[2 * (ph)][nf], 0, 0, 0);                        \
      acc[2 * (ph)][nf] = __builtin_amdgcn_mfma_f32_16x16x32_bf16(            \
          a01, bF[nf][1], acc[2 * (ph)][nf], 0, 0, 0);                        \
      acc[2 * (ph) + 1][nf] = __builtin_amdgcn_mfma_f32_16x16x32_bf16(        \
          a10, bF[nf][0], acc[2 * (ph) + 1][nf], 0, 0, 0);                    \
      acc[2 * (ph) + 1][nf] = __builtin_amdgcn_mfma_f32_16x16x32_bf16(        \
          a11, bF[nf][1], acc[2 * (ph) + 1][nf], 0, 0, 0);                    \
    }                                                                         \
    __builtin_amdgcn_s_setprio(0);                                            \
  }

  for (int t = 0; t < NKT; ++t) {
    const int db      = t & 1;
    const char* Ab    = (const char*)As[db];
    const char* Bb    = (const char*)Bs[db];
    char* Aw          = (char*)As[db ^ 1];
    char* Bw          = (char*)Bs[db ^ 1];
    const int kt      = (t + 1) * BKK;
    const bool more   = (t < NKT - 1);

    // ---- phase 0 (tile boundary) ----
    asm volatile("s_waitcnt vmcnt(2)" ::: "memory");  // B0-3,A0,A2 of t landed
    __builtin_amdgcn_s_barrier();
    bf16x8 bF[4][2];
#pragma unroll
    for (int nf = 0; nf < 4; ++nf) {
      bF[nf][0] = *(const bf16x8*)(Bb + boff0 + nf * 2048);
      bF[nf][1] = *(const bf16x8*)(Bb + boff1 + nf * 2048);
    }
    PHASE(0, if (more) { STAGE_Q(pb, Bw, 0, kt); STAGE_Q(pb, Bw, 1, kt); });
    // ---- phase 1 ----
    PHASE(1, if (more) { STAGE_Q(pb, Bw, 2, kt); STAGE_Q(pb, Bw, 3, kt); });
    // ---- phase 2 ----
    if (more) { asm volatile("s_waitcnt vmcnt(4)" ::: "memory"); }
    else      { asm volatile("s_waitcnt vmcnt(0)" ::: "memory"); }
    __builtin_amdgcn_s_barrier();                     // A1,A3 of t landed
    PHASE(2, if (more) { STAGE_Q(pa, Aw, 0, kt); STAGE_Q(pa, Aw, 2, kt); });
    // ---- phase 3 ----
    PHASE(3, if (more) { STAGE_Q(pa, Aw, 1, kt); STAGE_Q(pa, Aw, 3, kt); });
  }

  // epilogue: e = exp(2s); rowsum[row] += e; rowsum[col] += e if off-diag
  const int r4 = lane >> 4;
  const int cl = lane & 15;

  float rowpart[8][4];
  float colpart[4] = {0.f, 0.f, 0.f, 0.f};

  if (diag) {
#pragma unroll
    for (int mm = 0; mm < 8; ++mm)
#pragma unroll
      for (int r = 0; r < 4; ++r) {
        int grow = bi * BMM + wm * 128 + mm * 16 + r4 * 4 + r;
        float s = 0.f;
#pragma unroll
        for (int nf = 0; nf < 4; ++nf) {
          int gcol = bj * BMM + wn * 64 + nf * 16 + cl;
          float e  = __expf(2.0f * acc[mm][nf][r]);
          s += (grow == gcol) ? 0.f : e;
        }
        rowpart[mm][r] = s;
      }
  } else {
#pragma unroll
    for (int mm = 0; mm < 8; ++mm)
#pragma unroll
      for (int r = 0; r < 4; ++r) {
        float s = 0.f;
#pragma unroll
        for (int nf = 0; nf < 4; ++nf) {
          float e = __expf(2.0f * acc[mm][nf][r]);
          s += e;
          colpart[nf] += e;
        }
        rowpart[mm][r] = s;
      }
  }

#pragma unroll
  for (int mm = 0; mm < 8; ++mm)
#pragma unroll
    for (int r = 0; r < 4; ++r) {
      float s = rowpart[mm][r];
      s += __shfl_xor(s, 1);
      s += __shfl_xor(s, 2);
      s += __shfl_xor(s, 4);
      s += __shfl_xor(s, 8);
      if (cl == 0) {
        int grow = bi * BMM + wm * 128 + mm * 16 + r4 * 4 + r;
        atomicAdd(&rowsum[grow], s);
      }
    }

  if (!diag) {
#pragma unroll
    for (int nf = 0; nf < 4; ++nf) {
      float c = colpart[nf];
      c += __shfl_xor(c, 16);
      c += __shfl_xor(c, 32);
      if (r4 == 0) {
        int gcol = bj * BMM + wn * 64 + nf * 16 + cl;
        atomicAdd(&rowsum[gcol], c);
      }
    }
  }
}

// ---- Kernel 3: finalize loss ---------------------------------------------
__global__ __launch_bounds__(256) void finalize_kernel(
    const float* __restrict__ rowsum, const float* __restrict__ posp,
    float* __restrict__ out) {
  __shared__ float ws4[4];
  int tid = threadIdx.x;
  float v = 0.f;
  for (int i = tid; i < NROWS; i += 256) v += logf(rowsum[i]);
  for (int i = tid; i < 1024; i += 256) v -= posp[i];
#pragma unroll
  for (int off = 32; off; off >>= 1) v += __shfl_xor(v, off);
  if ((tid & 63) == 0) ws4[tid >> 6] = v;
  __syncthreads();
  if (tid == 0)
    out[0] = (ws4[0] + ws4[1] + ws4[2] + ws4[3]) / (float)NROWS;
}

extern "C" void kernel_launch(void* const* d_in, const int* in_sizes, int n_in,
                              void* d_out, int out_size, void* d_ws,
                              size_t ws_size, hipStream_t stream) {
  const float* zi = (const float*)d_in[0];
  const float* zj = (const float*)d_in[1];
  float* out      = (float*)d_out;

  char* ws          = (char*)d_ws;
  unsigned short* p = (unsigned short*)ws;                        // 8 MB bf16
  float* rowsum     = (float*)(ws + (size_t)NROWS * DIM * 2);     // 32 KB
  float* posp       = rowsum + NROWS;                             // 4 KB

  normalize_pos_kernel<<<NB / 4, 256, 0, stream>>>(zi, zj, p, rowsum, posp);
  simexp_kernel<<<NTRI, 512, 0, stream>>>(p, rowsum);
  finalize_kernel<<<1, 256, 0, stream>>>(rowsum, posp, out);
}

// Round 6
// 99.037 us; speedup vs baseline: 1.0815x; 1.0815x over previous
//
#include <hip/hip_runtime.h>
#include <hip/hip_bf16.h>
#include <stdint.h>

#define NB    4096
#define NROWS 8192
#define DIM   512
#define BM    128
#define BK    64
#define NKS   (DIM / BK)              // 8 K-steps
#define NBLK  2176                    // 8 XCDs x 272 (96 early-exit)

typedef __attribute__((ext_vector_type(8))) short          bf16x8;
typedef __attribute__((ext_vector_type(4))) float          f32x4;
typedef __attribute__((ext_vector_type(8))) unsigned short u16x8;

__device__ __forceinline__ unsigned short f2bf(float f) {
  uint32_t u = __float_as_uint(f);
  u += 0x7fffu + ((u >> 16) & 1u);   // round-to-nearest-even
  return (unsigned short)(u >> 16);
}
__device__ __forceinline__ float bf2f(unsigned short h) {
  return __uint_as_float(((uint32_t)h) << 16);
}
__device__ __forceinline__ void gload_lds16(const void* g, void* l) {
  __builtin_amdgcn_global_load_lds(
      (const __attribute__((address_space(1))) void*)g,
      (__attribute__((address_space(3))) void*)l, 16, 0, 0);
}

// ---- Kernel 1: normalize rows -> bf16 P, fused pos partials, zero rowsum --
__global__ __launch_bounds__(256) void normalize_pos_kernel(
    const float* __restrict__ zi, const float* __restrict__ zj,
    unsigned short* __restrict__ p, float* __restrict__ rowsum,
    float* __restrict__ posp) {
  __shared__ float ws4[4];
  const int wave = threadIdx.x >> 6;
  const int lane = threadIdx.x & 63;
  const int i    = blockIdx.x * 4 + wave;

  int gt = blockIdx.x * 256 + threadIdx.x;
  if (gt < NROWS) rowsum[gt] = 0.f;

  const float4* sa = (const float4*)(zi + (size_t)i * DIM);
  const float4* sb = (const float4*)(zj + (size_t)i * DIM);
  float4 a0 = sa[lane * 2], a1 = sa[lane * 2 + 1];
  float4 b0 = sb[lane * 2], b1 = sb[lane * 2 + 1];
  float va[8] = {a0.x, a0.y, a0.z, a0.w, a1.x, a1.y, a1.z, a1.w};
  float vb[8] = {b0.x, b0.y, b0.z, b0.w, b1.x, b1.y, b1.z, b1.w};
  float ssa = 0.f, ssb = 0.f;
#pragma unroll
  for (int j = 0; j < 8; ++j) { ssa += va[j] * va[j]; ssb += vb[j] * vb[j]; }
#pragma unroll
  for (int off = 32; off; off >>= 1) {
    ssa += __shfl_xor(ssa, off);
    ssb += __shfl_xor(ssb, off);
  }
  float inva = rsqrtf(ssa), invb = rsqrtf(ssb);
  u16x8 ha, hb;
#pragma unroll
  for (int j = 0; j < 8; ++j) { ha[j] = f2bf(va[j] * inva); hb[j] = f2bf(vb[j] * invb); }
  *(u16x8*)(p + (size_t)i * DIM + lane * 8)        = ha;
  *(u16x8*)(p + (size_t)(i + NB) * DIM + lane * 8) = hb;

  float d = 0.f;
#pragma unroll
  for (int j = 0; j < 8; ++j) d += bf2f(ha[j]) * bf2f(hb[j]);
#pragma unroll
  for (int off = 32; off; off >>= 1) d += __shfl_xor(d, off);
  if (lane == 0) ws4[wave] = d;
  __syncthreads();
  if (threadIdx.x == 0)
    posp[blockIdx.x] = 4.0f * (ws4[0] + ws4[1] + ws4[2] + ws4[3]);
}

// ---- Kernel 2: symmetric fused S = 2*P*P^T -> exp -> row+col sums ---------
// 128x128 tile, BK=64, single-buffered LDS, plain __syncthreads loop
// (R1 structure — best measured per-FLOP efficiency this session), with
// R3's supertile XCD mapping (FETCH 16.5 MB).
// LDS rows 128B, 8 chunks of 16B, chunk swizzled by chunk^=(row&7) via
// pre-swizzled global source (linear LDS dest) — R5-measured conflict-free.
__global__ __launch_bounds__(256) void simexp_kernel(
    const unsigned short* __restrict__ p, float* __restrict__ rowsum) {
  __shared__ __align__(16) unsigned short As[BM * BK];   // 16 KB
  __shared__ __align__(16) unsigned short Bs[BM * BK];   // 16 KB

  const int x = blockIdx.x & 7;          // XCD (round-robin heuristic)
  const int l = blockIdx.x >> 3;         // 0..271 local index
  int bi, bj;
  if (x < 6) {
    if (l >= 256) return;                // uniform early-exit, before barriers
    const int sqi[6] = {0, 0, 0, 1, 1, 2};
    const int sqj[6] = {1, 2, 3, 2, 3, 3};
    bi = sqi[x] * 16 + (l >> 4);
    bj = sqj[x] * 16 + (l & 15);
  } else {
    int s  = (x == 6) ? 0 : 2;
    int ll = l;
    if (ll >= 136) { ll -= 136; s += 1; }
    int i = 0;
    while ((i + 1) * (33 - (i + 1)) / 2 <= ll) ++i;
    int j = i + (ll - i * (33 - i) / 2);
    bi = s * 16 + i;
    bj = s * 16 + j;
  }
  const bool diag = (bi == bj);

  const int tid  = threadIdx.x;
  const int wave = tid >> 6;
  const int lane = tid & 63;
  const int wm   = wave >> 1;
  const int wn   = wave & 1;
  const int frow = lane & 15;
  const int kc   = lane >> 4;      // 0..3

  const unsigned short* pa = p + (size_t)(bi * BM) * DIM;
  const unsigned short* pb = p + (size_t)(bj * BM) * DIM;

  // staging: per wave 4 issues per operand; issue q covers rows wave*32+q*8
  const int srow8 = lane >> 3;               // 0..7
  const int gch   = (lane & 7) ^ srow8;      // pre-swizzled 16B chunk

  // ds_read byte offsets: row*128 + ((kk*4+kc)^(row&7))*16, kk in {0,1}
  int offA[4][2], offB[4][2];
#pragma unroll
  for (int m = 0; m < 4; ++m) {
    int row = wm * 64 + m * 16 + frow;
#pragma unroll
    for (int kk = 0; kk < 2; ++kk)
      offA[m][kk] = row * 128 + ((kk * 4 + kc) ^ (row & 7)) * 16;
  }
#pragma unroll
  for (int n = 0; n < 4; ++n) {
    int row = wn * 64 + n * 16 + frow;
#pragma unroll
    for (int kk = 0; kk < 2; ++kk)
      offB[n][kk] = row * 128 + ((kk * 4 + kc) ^ (row & 7)) * 16;
  }

  f32x4 acc[4][4] = {};

  for (int t = 0; t < NKS; ++t) {
    const int k0 = t * BK;
#pragma unroll
    for (int q = 0; q < 4; ++q) {
      int rbase = wave * 32 + q * 8;
      gload_lds16(pa + (size_t)(rbase + srow8) * DIM + k0 + gch * 8,
                  (char*)As + rbase * 128);
      gload_lds16(pb + (size_t)(rbase + srow8) * DIM + k0 + gch * 8,
                  (char*)Bs + rbase * 128);
    }
    __syncthreads();

    bf16x8 af[4][2], bf_[4][2];
#pragma unroll
    for (int m = 0; m < 4; ++m) {
      af[m][0] = *(const bf16x8*)((const char*)As + offA[m][0]);
      af[m][1] = *(const bf16x8*)((const char*)As + offA[m][1]);
    }
#pragma unroll
    for (int n = 0; n < 4; ++n) {
      bf_[n][0] = *(const bf16x8*)((const char*)Bs + offB[n][0]);
      bf_[n][1] = *(const bf16x8*)((const char*)Bs + offB[n][1]);
    }
#pragma unroll
    for (int m = 0; m < 4; ++m)
#pragma unroll
      for (int n = 0; n < 4; ++n) {
        acc[m][n] = __builtin_amdgcn_mfma_f32_16x16x32_bf16(
            af[m][0], bf_[n][0], acc[m][n], 0, 0, 0);
        acc[m][n] = __builtin_amdgcn_mfma_f32_16x16x32_bf16(
            af[m][1], bf_[n][1], acc[m][n], 0, 0, 0);
      }
    __syncthreads();
  }

  // epilogue: e = exp(2s); rowsum[row] += e; rowsum[col] += e if off-diag
  const int r4 = lane >> 4;   // C/D: col = lane&15, row = (lane>>4)*4 + reg
  const int cl = lane & 15;

  float rowpart[4][4];
  float colpart[4] = {0.f, 0.f, 0.f, 0.f};

  if (diag) {
#pragma unroll
    for (int m = 0; m < 4; ++m)
#pragma unroll
      for (int r = 0; r < 4; ++r) {
        int grow = bi * BM + wm * 64 + m * 16 + r4 * 4 + r;
        float s = 0.f;
#pragma unroll
        for (int n = 0; n < 4; ++n) {
          int gcol = bj * BM + wn * 64 + n * 16 + cl;
          float e  = __expf(2.0f * acc[m][n][r]);
          s += (grow == gcol) ? 0.f : e;
        }
        rowpart[m][r] = s;
      }
  } else {
#pragma unroll
    for (int m = 0; m < 4; ++m)
#pragma unroll
      for (int r = 0; r < 4; ++r) {
        float s = 0.f;
#pragma unroll
        for (int n = 0; n < 4; ++n) {
          float e = __expf(2.0f * acc[m][n][r]);
          s += e;
          colpart[n] += e;
        }
        rowpart[m][r] = s;
      }
  }

#pragma unroll
  for (int m = 0; m < 4; ++m)
#pragma unroll
    for (int r = 0; r < 4; ++r) {
      float s = rowpart[m][r];
      s += __shfl_xor(s, 1);
      s += __shfl_xor(s, 2);
      s += __shfl_xor(s, 4);
      s += __shfl_xor(s, 8);
      if (cl == 0) {
        int grow = bi * BM + wm * 64 + m * 16 + r4 * 4 + r;
        atomicAdd(&rowsum[grow], s);
      }
    }

  if (!diag) {
#pragma unroll
    for (int n = 0; n < 4; ++n) {
      float c = colpart[n];
      c += __shfl_xor(c, 16);
      c += __shfl_xor(c, 32);
      if (r4 == 0) {
        int gcol = bj * BM + wn * 64 + n * 16 + cl;
        atomicAdd(&rowsum[gcol], c);
      }
    }
  }
}

// ---- Kernel 3: finalize loss ---------------------------------------------
__global__ __launch_bounds__(256) void finalize_kernel(
    const float* __restrict__ rowsum, const float* __restrict__ posp,
    float* __restrict__ out) {
  __shared__ float ws4[4];
  int tid = threadIdx.x;
  float v = 0.f;
  for (int i = tid; i < NROWS; i += 256) v += logf(rowsum[i]);
  for (int i = tid; i < 1024; i += 256) v -= posp[i];
#pragma unroll
  for (int off = 32; off; off >>= 1) v += __shfl_xor(v, off);
  if ((tid & 63) == 0) ws4[tid >> 6] = v;
  __syncthreads();
  if (tid == 0)
    out[0] = (ws4[0] + ws4[1] + ws4[2] + ws4[3]) / (float)NROWS;
}

extern "C" void kernel_launch(void* const* d_in, const int* in_sizes, int n_in,
                              void* d_out, int out_size, void* d_ws,
                              size_t ws_size, hipStream_t stream) {
  const float* zi = (const float*)d_in[0];
  const float* zj = (const float*)d_in[1];
  float* out      = (float*)d_out;

  char* ws          = (char*)d_ws;
  unsigned short* p = (unsigned short*)ws;                        // 8 MB bf16
  float* rowsum     = (float*)(ws + (size_t)NROWS * DIM * 2);     // 32 KB
  float* posp       = rowsum + NROWS;                             // 4 KB

  normalize_pos_kernel<<<NB / 4, 256, 0, stream>>>(zi, zj, p, rowsum, posp);
  simexp_kernel<<<NBLK, 256, 0, stream>>>(p, rowsum);
  finalize_kernel<<<1, 256, 0, stream>>>(rowsum, posp, out);
}